// Round 1
// baseline (691.655 us; speedup 1.0000x reference)
//
#include <hip/hip_runtime.h>
#include <cstdint>

typedef __fp16 f16x8 __attribute__((ext_vector_type(8)));
typedef __fp16 f16x4 __attribute__((ext_vector_type(4)));
typedef float  f32x4 __attribute__((ext_vector_type(4)));

static constexpr int NDIM = 1024;  // N = H*W = C = KC = VC

// ---------------- workspace layout (bytes) ----------------
// phase A (proj):   W3 fp16 [3072][1024] @0 ; bias3 f32 [3072] @6291456 ; xT fp16 [32][1024][1024] @6303744
// phase B (attn):   S f32 [32][1024][1024] @0   (reuses phase-A region, lifetimes disjoint)
// persistent:       QKV fp16 [32][3072][1024] @134217728  (q|k|v per batch)
// phase C:          stats float2 [32768] overlays dead k[0]; attnT[b] fp16 overlays dead q[b]
static constexpr long long OFF_W     = 0;
static constexpr long long OFF_BIAS  = 6291456;
static constexpr long long OFF_XT    = 6303744;
static constexpr long long OFF_S     = 0;
static constexpr long long OFF_QKV   = 134217728;
static constexpr long long OFF_STATS = OFF_QKV + 2097152;  // over k[0]
// total required: OFF_QKV + 32*3072*1024*2 = 335,544,320 bytes

__device__ __forceinline__ void async16(__fp16* lds, const __fp16* g) {
  __builtin_amdgcn_global_load_lds(
      (const __attribute__((address_space(1))) void*)g,
      (__attribute__((address_space(3))) void*)lds, 16, 0, 0);
}

// ---------------- small prep kernels ----------------
__global__ __launch_bounds__(256) void cast_w(const float* __restrict__ Wq,
                                              const float* __restrict__ Wk,
                                              const float* __restrict__ Wv,
                                              __fp16* __restrict__ W3) {
  const int i = blockIdx.x * 256 + threadIdx.x;  // 786432 float4-chunks
  const int which = i >> 18;                     // 262144 per matrix
  const int j = i & 262143;
  const float* src = which == 0 ? Wq : (which == 1 ? Wk : Wv);
  const float4 v = ((const float4*)src)[j];
  f16x4 o = {(__fp16)v.x, (__fp16)v.y, (__fp16)v.z, (__fp16)v.w};
  ((f16x4*)W3)[i] = o;
}

__global__ __launch_bounds__(256) void pack_bias(const float* __restrict__ bq,
                                                 const float* __restrict__ bk,
                                                 const float* __restrict__ bv,
                                                 float* __restrict__ b3) {
  const int i = blockIdx.x * 256 + threadIdx.x;
  if (i < 1024) b3[i] = bq[i];
  else if (i < 2048) b3[i] = bk[i - 1024];
  else if (i < 3072) b3[i] = bv[i - 2048];
}

__global__ __launch_bounds__(256) void transpose_cast_x(const float* __restrict__ x,
                                                        __fp16* __restrict__ xT) {
  __shared__ float t[32][33];
  const int b = blockIdx.z;
  const int n0 = blockIdx.x * 32, c0 = blockIdx.y * 32;
  const float* xb = x + (long long)b * NDIM * NDIM;
  __fp16* ob = xT + (long long)b * NDIM * NDIM;
  const int tx = threadIdx.x & 31, ty = threadIdx.x >> 5;
#pragma unroll
  for (int i = ty; i < 32; i += 8)
    t[i][tx] = xb[(long long)(c0 + i) * NDIM + n0 + tx];
  __syncthreads();
#pragma unroll
  for (int i = ty; i < 32; i += 8)
    ob[(long long)(n0 + i) * NDIM + c0 + tx] = (__fp16)t[tx][i];
}

// ---------------- m97-style 128x128 gemm_bt (A[M][K] * B^T[N][K]) ----------------
// EPI 0: fp16 out + bias[row]; EPI 1: f32 out; EPI 2: f32 out = gamma*acc + X
template <int EPI>
__global__ __launch_bounds__(256)
void gemm_bt(const __fp16* __restrict__ A, const __fp16* __restrict__ B,
             void* __restrict__ Cout, const float* __restrict__ bias,
             const float* __restrict__ X, const float* __restrict__ gamma,
             int M, int N, int K, long long sA, long long sB, long long sC) {
  __shared__ alignas(16) __fp16 As[128 * 32];
  __shared__ alignas(16) __fp16 Bs[128 * 32];

  const int tid  = threadIdx.x;
  const int wave = tid >> 6;
  const int lane = tid & 63;
  const int b    = blockIdx.z;
  const int m0   = blockIdx.y * 128;
  const int n0   = blockIdx.x * 128;

  A += (long long)b * sA;
  B += (long long)b * sB;

  // staging: 512 16B-chunks per tile; chunk c -> row c>>2, col (c&3)*8 halves
  const int c0 = tid, c1 = tid + 256;
  const int ar0 = c0 >> 2, ac0 = (c0 & 3) * 8;
  const int ar1 = c1 >> 2, ac1 = (c1 & 3) * 8;

  const int wr = (wave >> 1) * 64;  // wave quadrant
  const int wc = (wave & 1) * 64;
  const int fr = lane & 15;
  const int fk = (lane >> 4) * 8;

  f32x4 acc[4][4];
#pragma unroll
  for (int i = 0; i < 4; i++)
#pragma unroll
    for (int j = 0; j < 4; j++) acc[i][j] = f32x4{0.f, 0.f, 0.f, 0.f};

  for (int k0 = 0; k0 < K; k0 += 32) {
    async16(As + c0 * 8, A + (long long)(m0 + ar0) * K + k0 + ac0);
    async16(As + c1 * 8, A + (long long)(m0 + ar1) * K + k0 + ac1);
    async16(Bs + c0 * 8, B + (long long)(n0 + ar0) * K + k0 + ac0);
    async16(Bs + c1 * 8, B + (long long)(n0 + ar1) * K + k0 + ac1);
    __syncthreads();  // drains vmcnt before compute

    f16x8 af[4], bf[4];
#pragma unroll
    for (int mi = 0; mi < 4; mi++)
      af[mi] = *(const f16x8*)&As[(wr + mi * 16 + fr) * 32 + fk];
#pragma unroll
    for (int ni = 0; ni < 4; ni++)
      bf[ni] = *(const f16x8*)&Bs[(wc + ni * 16 + fr) * 32 + fk];
#pragma unroll
    for (int mi = 0; mi < 4; mi++)
#pragma unroll
      for (int ni = 0; ni < 4; ni++)
        acc[mi][ni] = __builtin_amdgcn_mfma_f32_16x16x32_f16(af[mi], bf[ni], acc[mi][ni], 0, 0, 0);
    __syncthreads();
  }

  // epilogue: C/D layout col=lane&15, row=(lane>>4)*4+reg  [m89-verified]
  const int colb = n0 + wc + fr;
  const int rowb = m0 + wr + (lane >> 4) * 4;
  float g = 0.f;
  if (EPI == 2) g = gamma[0];
#pragma unroll
  for (int mi = 0; mi < 4; mi++) {
#pragma unroll
    for (int r = 0; r < 4; r++) {
      const int row = rowb + mi * 16 + r;
      const long long rb = (long long)b * sC + (long long)row * N;
      float bb = 0.f;
      if (EPI == 0) bb = bias[row];
#pragma unroll
      for (int ni = 0; ni < 4; ni++) {
        const int col = colb + ni * 16;
        const float v = acc[mi][ni][r];
        if (EPI == 0) {
          ((__fp16*)Cout)[rb + col] = (__fp16)(v + bb);
        } else if (EPI == 1) {
          ((float*)Cout)[rb + col] = v;
        } else {
          ((float*)Cout)[rb + col] = g * v + X[rb + col];
        }
      }
    }
  }
}

// ---------------- softmax ----------------
__global__ __launch_bounds__(256) void row_stats(const float* __restrict__ S,
                                                 float2* __restrict__ stats) {
  const int row = blockIdx.x * 4 + (threadIdx.x >> 6);  // 0..32767
  const int lane = threadIdx.x & 63;
  const float4* r = (const float4*)(S + (long long)row * NDIM);
  float4 v[4];
  float m = -3.4e38f;
#pragma unroll
  for (int j = 0; j < 4; j++) {
    v[j] = r[lane + 64 * j];
    m = fmaxf(m, fmaxf(fmaxf(v[j].x, v[j].y), fmaxf(v[j].z, v[j].w)));
  }
#pragma unroll
  for (int o = 32; o; o >>= 1) m = fmaxf(m, __shfl_xor(m, o));
  float s = 0.f;
#pragma unroll
  for (int j = 0; j < 4; j++)
    s += __expf(v[j].x - m) + __expf(v[j].y - m) + __expf(v[j].z - m) + __expf(v[j].w - m);
#pragma unroll
  for (int o = 32; o; o >>= 1) s += __shfl_xor(s, o);
  if (lane == 0) stats[row] = make_float2(m, 1.f / s);
}

// exp-normalize + transpose: attnT[j][i] = exp(S[i][j]-m[i])/s[i], fp16
__global__ __launch_bounds__(256) void softmax_transpose(const float* __restrict__ S,
                                                         const float2* __restrict__ stats,
                                                         __fp16* __restrict__ attnT) {
  __shared__ __fp16 t[64][72];  // [j][i], padded
  const int b = blockIdx.z;
  const int i0 = blockIdx.y * 64, j0 = blockIdx.x * 64;
  const float* Sb = S + (long long)b * NDIM * NDIM;
  const float2* st = stats + b * NDIM;
  const int tr = threadIdx.x >> 4;        // 0..15
  const int tc = (threadIdx.x & 15) * 4;  // 0..60
#pragma unroll
  for (int it = 0; it < 4; it++) {
    const int i = tr + 16 * it;
    const float4 vv = *(const float4*)&Sb[(long long)(i0 + i) * NDIM + j0 + tc];
    const float2 ms = st[i0 + i];
    t[tc + 0][i] = (__fp16)(__expf(vv.x - ms.x) * ms.y);
    t[tc + 1][i] = (__fp16)(__expf(vv.y - ms.x) * ms.y);
    t[tc + 2][i] = (__fp16)(__expf(vv.z - ms.x) * ms.y);
    t[tc + 3][i] = (__fp16)(__expf(vv.w - ms.x) * ms.y);
  }
  __syncthreads();
  __fp16* Ab = attnT + (long long)b * 3145728;  // overlays q[b]
#pragma unroll
  for (int it = 0; it < 4; it++) {
    const int j = tr + 16 * it;
    f16x4 o = {t[j][tc], t[j][tc + 1], t[j][tc + 2], t[j][tc + 3]};
    *(f16x4*)&Ab[(long long)(j0 + j) * NDIM + i0 + tc] = o;
  }
}

// ---------------- launch ----------------
extern "C" void kernel_launch(void* const* d_in, const int* in_sizes, int n_in,
                              void* d_out, int out_size, void* d_ws, size_t ws_size,
                              hipStream_t stream) {
  const float* x     = (const float*)d_in[0];
  const float* Wq    = (const float*)d_in[1];
  const float* bq    = (const float*)d_in[2];
  const float* Wk    = (const float*)d_in[3];
  const float* bk    = (const float*)d_in[4];
  const float* Wv    = (const float*)d_in[5];
  const float* bv    = (const float*)d_in[6];
  const float* gamma = (const float*)d_in[7];
  char* ws = (char*)d_ws;

  __fp16* W3    = (__fp16*)(ws + OFF_W);
  float*  bias3 = (float*)(ws + OFF_BIAS);
  __fp16* xT    = (__fp16*)(ws + OFF_XT);
  float*  S     = (float*)(ws + OFF_S);
  __fp16* QKV   = (__fp16*)(ws + OFF_QKV);
  float2* stats = (float2*)(ws + OFF_STATS);
  float*  out   = (float*)d_out;

  cast_w<<<3072, 256, 0, stream>>>(Wq, Wk, Wv, W3);
  pack_bias<<<12, 256, 0, stream>>>(bq, bk, bv, bias3);
  transpose_cast_x<<<dim3(32, 32, 32), 256, 0, stream>>>(x, xT);

  // QKV[b] = W3 (3072x1024) * xT[b]^T  (+bias), fp16
  gemm_bt<0><<<dim3(8, 24, 32), 256, 0, stream>>>(
      W3, xT, QKV, bias3, nullptr, nullptr,
      3072, 1024, 1024, 0LL, 1048576LL, 3145728LL);

  // S[b] = q[b] * k[b]^T, f32
  gemm_bt<1><<<dim3(8, 8, 32), 256, 0, stream>>>(
      QKV, QKV + 1048576, S, nullptr, nullptr, nullptr,
      1024, 1024, 1024, 3145728LL, 3145728LL, 1048576LL);

  row_stats<<<8192, 256, 0, stream>>>(S, stats);
  softmax_transpose<<<dim3(16, 16, 32), 256, 0, stream>>>(S, stats, QKV);

  // out[b] = gamma * (v[b] * attnT[b]^T) + x[b], f32 -> d_out
  gemm_bt<2><<<dim3(8, 8, 32), 256, 0, stream>>>(
      QKV + 2097152, QKV, out, nullptr, x, gamma,
      1024, 1024, 1024, 3145728LL, 3145728LL, 1048576LL);
}

// Round 2
// 542.503 us; speedup vs baseline: 1.2749x; 1.2749x over previous
//
#include <hip/hip_runtime.h>
#include <cstdint>

typedef __fp16 f16x8 __attribute__((ext_vector_type(8)));
typedef __fp16 f16x4 __attribute__((ext_vector_type(4)));
typedef float  f32x4 __attribute__((ext_vector_type(4)));

static constexpr int NDIM = 1024;  // N = H*W = C = KC = VC

// ---------------- workspace layout (bytes) ----------------
static constexpr long long OFF_W     = 0;
static constexpr long long OFF_BIAS  = 6291456;
static constexpr long long OFF_XT    = 6303744;
static constexpr long long OFF_S     = 0;
static constexpr long long OFF_QKV   = 134217728;
static constexpr long long OFF_STATS = OFF_QKV + 2097152;  // over k[0]
// total required: OFF_QKV + 32*3072*1024*2 = 335,544,320 bytes

__device__ __forceinline__ void async16(__fp16* lds, const __fp16* g) {
  __builtin_amdgcn_global_load_lds(
      (const __attribute__((address_space(1))) void*)g,
      (__attribute__((address_space(3))) void*)lds, 16, 0, 0);
}

// ---------------- small prep kernels ----------------
__global__ __launch_bounds__(256) void cast_w(const float* __restrict__ Wq,
                                              const float* __restrict__ Wk,
                                              const float* __restrict__ Wv,
                                              __fp16* __restrict__ W3) {
  const int i = blockIdx.x * 256 + threadIdx.x;
  const int which = i >> 18;
  const int j = i & 262143;
  const float* src = which == 0 ? Wq : (which == 1 ? Wk : Wv);
  const float4 v = ((const float4*)src)[j];
  f16x4 o = {(__fp16)v.x, (__fp16)v.y, (__fp16)v.z, (__fp16)v.w};
  ((f16x4*)W3)[i] = o;
}

__global__ __launch_bounds__(256) void pack_bias(const float* __restrict__ bq,
                                                 const float* __restrict__ bk,
                                                 const float* __restrict__ bv,
                                                 float* __restrict__ b3) {
  const int i = blockIdx.x * 256 + threadIdx.x;
  if (i < 1024) b3[i] = bq[i];
  else if (i < 2048) b3[i] = bk[i - 1024];
  else if (i < 3072) b3[i] = bv[i - 2048];
}

__global__ __launch_bounds__(256) void transpose_cast_x(const float* __restrict__ x,
                                                        __fp16* __restrict__ xT) {
  __shared__ float t[32][33];
  const int b = blockIdx.z;
  const int n0 = blockIdx.x * 32, c0 = blockIdx.y * 32;
  const float* xb = x + (long long)b * NDIM * NDIM;
  __fp16* ob = xT + (long long)b * NDIM * NDIM;
  const int tx = threadIdx.x & 31, ty = threadIdx.x >> 5;
#pragma unroll
  for (int i = ty; i < 32; i += 8)
    t[i][tx] = xb[(long long)(c0 + i) * NDIM + n0 + tx];
  __syncthreads();
#pragma unroll
  for (int i = ty; i < 32; i += 8)
    ob[(long long)(n0 + i) * NDIM + c0 + tx] = (__fp16)t[tx][i];
}

// ---------------- 256x256 8-wave phase-scheduled gemm_bt (A[M][K] * B^T[N][K]) ----------------
// LDS: A [2 buf][256 rows][64 cols] staged as 2 row-halves, read-swizzle byte^=((row&7)<<4)
//      B [2 buf][2 kslice][256 rows][32 cols], read-swizzle byte^=((row&3)<<4)
// Per K-tile (BK=64): 4 phases, each {stage 1 half of tile t+1; ds_read; 16 MFMA}.
// Waits: vmcnt(2)+barrier at tile top (A halves + B-ks0 of t resident);
//        vmcnt(4)+barrier mid-tile (B-ks1 of t resident). Never vmcnt(0) in loop.

#define STAGE_A(NXT, h, kk)                                                        \
  async16(&As[(NXT)*16384 + (h)*8192 + 0*4096 + tid*8],                            \
          A + (long long)(m0 + (h)*128 + 0*64 + a_r) * K + (kk) + a_c);            \
  async16(&As[(NXT)*16384 + (h)*8192 + 1*4096 + tid*8],                            \
          A + (long long)(m0 + (h)*128 + 1*64 + a_r) * K + (kk) + a_c);

#define STAGE_B(NXT, s, kk)                                                        \
  async16(&Bs[(NXT)*16384 + (s)*8192 + 0*4096 + tid*8],                            \
          Bp + (long long)(n0 + 0*128 + b_r) * K + (kk) + (s)*32 + b_c);           \
  async16(&Bs[(NXT)*16384 + (s)*8192 + 1*4096 + tid*8],                            \
          Bp + (long long)(n0 + 1*128 + b_r) * K + (kk) + (s)*32 + b_c);

#define LOAD_AF(CUR, ks)                                                           \
  _Pragma("unroll")                                                                \
  for (int mf = 0; mf < 8; ++mf)                                                   \
    af[mf] = *(const f16x8*)&As[(CUR)*16384 + aRow + mf*1024 + acol##ks];

#define LOAD_BF(CUR, ks, nfb)                                                      \
  bf[0] = *(const f16x8*)&Bs[(CUR)*16384 + (ks)*8192 + bRow + (nfb)*512 + bcol];   \
  bf[1] = *(const f16x8*)&Bs[(CUR)*16384 + (ks)*8192 + bRow + ((nfb)+1)*512 + bcol];

#define MFMA16(nfb)                                                                \
  __builtin_amdgcn_s_setprio(1);                                                   \
  _Pragma("unroll")                                                                \
  for (int mf = 0; mf < 8; ++mf) {                                                 \
    acc[mf][nfb]     = __builtin_amdgcn_mfma_f32_16x16x32_f16(af[mf], bf[0], acc[mf][nfb], 0, 0, 0);      \
    acc[mf][(nfb)+1] = __builtin_amdgcn_mfma_f32_16x16x32_f16(af[mf], bf[1], acc[mf][(nfb)+1], 0, 0, 0);  \
  }                                                                                \
  __builtin_amdgcn_s_setprio(0);

#define TILE(CUR, NXT, KNEXT)                                                      \
  asm volatile("s_waitcnt vmcnt(2)" ::: "memory");                                 \
  __builtin_amdgcn_s_barrier();                                                    \
  asm volatile("" ::: "memory");                                                   \
  STAGE_A(NXT, 0, KNEXT)                                                           \
  LOAD_AF(CUR, 0)                                                                  \
  LOAD_BF(CUR, 0, 0)                                                               \
  MFMA16(0)                                                                        \
  STAGE_A(NXT, 1, KNEXT)                                                           \
  LOAD_BF(CUR, 0, 2)                                                               \
  MFMA16(2)                                                                        \
  asm volatile("s_waitcnt vmcnt(4)" ::: "memory");                                 \
  __builtin_amdgcn_s_barrier();                                                    \
  asm volatile("" ::: "memory");                                                   \
  STAGE_B(NXT, 0, KNEXT)                                                           \
  LOAD_AF(CUR, 1)                                                                  \
  LOAD_BF(CUR, 1, 0)                                                               \
  MFMA16(0)                                                                        \
  STAGE_B(NXT, 1, KNEXT)                                                           \
  LOAD_BF(CUR, 1, 2)                                                               \
  MFMA16(2)

template <int EPI>
__global__ __launch_bounds__(512, 2)
void gemm256(const __fp16* __restrict__ Ag, const __fp16* __restrict__ Bg,
             void* __restrict__ Cout, const float* __restrict__ bias,
             const float* __restrict__ X, const float* __restrict__ gamma,
             int M, int N, int K, long long sA, long long sB, long long sC) {
  __shared__ alignas(16) __fp16 As[2 * 16384];
  __shared__ alignas(16) __fp16 Bs[2 * 16384];

  const int tid  = threadIdx.x;
  const int wid  = tid >> 6, lane = tid & 63;
  const int wm   = wid >> 2, wn = wid & 3;
  const int g    = lane >> 4, r = lane & 15;
  const int b    = blockIdx.z;
  const int m0   = blockIdx.y * 256;
  const int n0   = blockIdx.x * 256;

  const __fp16* A  = Ag + (long long)b * sA;
  const __fp16* Bp = Bg + (long long)b * sB;

  // staging address precompute (pre-swizzled global columns; LDS dest linear)
  const int a_r = tid >> 3;                              // row within 64-row issue block
  const int a_c = ((tid & 7) ^ ((tid >> 3) & 7)) * 8;    // swizzled source col (elems)
  const int b_r = tid >> 2;                              // row within 128-row issue block
  const int b_c = ((tid & 3) ^ ((tid >> 2) & 3)) * 8;

  // read-side fragment offsets (element units), swizzle matched to staging
  const int aRow  = (wm * 128 + r) * 64;
  const int acol0 = (((0 * 64) + g * 16) ^ ((r & 7) << 4)) >> 1;
  const int acol1 = (((1 * 64) + g * 16) ^ ((r & 7) << 4)) >> 1;
  const int bRow  = (wn * 64 + r) * 32;
  const int bcol  = ((g * 16) ^ ((r & 3) << 4)) >> 1;

  f16x8 af[8];
  f16x8 bf[2];
  f32x4 acc[8][4];
#pragma unroll
  for (int i = 0; i < 8; ++i)
#pragma unroll
    for (int j = 0; j < 4; ++j) acc[i][j] = f32x4{0.f, 0.f, 0.f, 0.f};

  // prologue: stage tile 0 (order must match steady state: A-m0, A-m1, B-k0, B-k1)
  STAGE_A(0, 0, 0)
  STAGE_A(0, 1, 0)
  STAGE_B(0, 0, 0)
  STAGE_B(0, 1, 0)

  for (int k0 = 0; k0 < K; k0 += 128) {
    const int kn1 = k0 + 64;                               // always < K (K multiple of 128)
    const int kn2 = (k0 + 128 < K) ? (k0 + 128) : 0;       // clamp: last prefetch is junk but in-bounds
    TILE(0, 1, kn1)
    TILE(1, 0, kn2)
  }

  // epilogue: C/D layout col=lane&15, row=(lane>>4)*4+reg
  const float g2 = (EPI == 2) ? gamma[0] : 0.f;
  const int ccol  = n0 + wn * 64 + (lane & 15);
  const int crow0 = m0 + wm * 128 + (lane >> 4) * 4;
#pragma unroll
  for (int mf = 0; mf < 8; ++mf) {
#pragma unroll
    for (int reg = 0; reg < 4; ++reg) {
      const int row = crow0 + mf * 16 + reg;
      const long long rb = (long long)b * sC + (long long)row * N;
      const float bb = (EPI == 0) ? bias[row] : 0.f;
#pragma unroll
      for (int nf = 0; nf < 4; ++nf) {
        const int col = ccol + nf * 16;
        const float v = acc[mf][nf][reg];
        if (EPI == 0)      ((__fp16*)Cout)[rb + col] = (__fp16)(v + bb);
        else if (EPI == 1) ((float*)Cout)[rb + col] = v;
        else               ((float*)Cout)[rb + col] = g2 * v + X[rb + col];
      }
    }
  }
}

// ---------------- softmax ----------------
__global__ __launch_bounds__(256) void row_stats(const float* __restrict__ S,
                                                 float2* __restrict__ stats) {
  const int row = blockIdx.x * 4 + (threadIdx.x >> 6);
  const int lane = threadIdx.x & 63;
  const float4* rp = (const float4*)(S + (long long)row * NDIM);
  float4 v[4];
  float m = -3.4e38f;
#pragma unroll
  for (int j = 0; j < 4; j++) {
    v[j] = rp[lane + 64 * j];
    m = fmaxf(m, fmaxf(fmaxf(v[j].x, v[j].y), fmaxf(v[j].z, v[j].w)));
  }
#pragma unroll
  for (int o = 32; o; o >>= 1) m = fmaxf(m, __shfl_xor(m, o));
  float s = 0.f;
#pragma unroll
  for (int j = 0; j < 4; j++)
    s += __expf(v[j].x - m) + __expf(v[j].y - m) + __expf(v[j].z - m) + __expf(v[j].w - m);
#pragma unroll
  for (int o = 32; o; o >>= 1) s += __shfl_xor(s, o);
  if (lane == 0) stats[row] = make_float2(m, 1.f / s);
}

__global__ __launch_bounds__(256) void softmax_transpose(const float* __restrict__ S,
                                                         const float2* __restrict__ stats,
                                                         __fp16* __restrict__ attnT) {
  __shared__ __fp16 t[64][72];
  const int b = blockIdx.z;
  const int i0 = blockIdx.y * 64, j0 = blockIdx.x * 64;
  const float* Sb = S + (long long)b * NDIM * NDIM;
  const float2* st = stats + b * NDIM;
  const int tr = threadIdx.x >> 4;
  const int tc = (threadIdx.x & 15) * 4;
#pragma unroll
  for (int it = 0; it < 4; it++) {
    const int i = tr + 16 * it;
    const float4 vv = *(const float4*)&Sb[(long long)(i0 + i) * NDIM + j0 + tc];
    const float2 ms = st[i0 + i];
    t[tc + 0][i] = (__fp16)(__expf(vv.x - ms.x) * ms.y);
    t[tc + 1][i] = (__fp16)(__expf(vv.y - ms.x) * ms.y);
    t[tc + 2][i] = (__fp16)(__expf(vv.z - ms.x) * ms.y);
    t[tc + 3][i] = (__fp16)(__expf(vv.w - ms.x) * ms.y);
  }
  __syncthreads();
  __fp16* Ab = attnT + (long long)b * 3145728;
#pragma unroll
  for (int it = 0; it < 4; it++) {
    const int j = tr + 16 * it;
    f16x4 o = {t[j][tc], t[j][tc + 1], t[j][tc + 2], t[j][tc + 3]};
    *(f16x4*)&Ab[(long long)(j0 + j) * NDIM + i0 + tc] = o;
  }
}

// ---------------- launch ----------------
extern "C" void kernel_launch(void* const* d_in, const int* in_sizes, int n_in,
                              void* d_out, int out_size, void* d_ws, size_t ws_size,
                              hipStream_t stream) {
  const float* x     = (const float*)d_in[0];
  const float* Wq    = (const float*)d_in[1];
  const float* bq    = (const float*)d_in[2];
  const float* Wk    = (const float*)d_in[3];
  const float* bk    = (const float*)d_in[4];
  const float* Wv    = (const float*)d_in[5];
  const float* bv    = (const float*)d_in[6];
  const float* gamma = (const float*)d_in[7];
  char* ws = (char*)d_ws;

  __fp16* W3    = (__fp16*)(ws + OFF_W);
  float*  bias3 = (float*)(ws + OFF_BIAS);
  __fp16* xT    = (__fp16*)(ws + OFF_XT);
  float*  S     = (float*)(ws + OFF_S);
  __fp16* QKV   = (__fp16*)(ws + OFF_QKV);
  float2* stats = (float2*)(ws + OFF_STATS);
  float*  out   = (float*)d_out;

  cast_w<<<3072, 256, 0, stream>>>(Wq, Wk, Wv, W3);
  pack_bias<<<12, 256, 0, stream>>>(bq, bk, bv, bias3);
  transpose_cast_x<<<dim3(32, 32, 32), 256, 0, stream>>>(x, xT);

  // QKV[b] = W3 (3072x1024) * xT[b]^T  (+bias), fp16
  gemm256<0><<<dim3(4, 12, 32), 512, 0, stream>>>(
      W3, xT, QKV, bias3, nullptr, nullptr,
      3072, 1024, 1024, 0LL, 1048576LL, 3145728LL);

  // S[b] = q[b] * k[b]^T, f32
  gemm256<1><<<dim3(4, 4, 32), 512, 0, stream>>>(
      QKV, QKV + 1048576, S, nullptr, nullptr, nullptr,
      1024, 1024, 1024, 3145728LL, 3145728LL, 1048576LL);

  row_stats<<<8192, 256, 0, stream>>>(S, stats);
  softmax_transpose<<<dim3(16, 16, 32), 256, 0, stream>>>(S, stats, QKV);

  // out[b] = gamma * (v[b] * attnT[b]^T) + x[b], f32 -> d_out
  gemm256<2><<<dim3(4, 4, 32), 512, 0, stream>>>(
      QKV + 2097152, QKV, out, nullptr, x, gamma,
      1024, 1024, 1024, 3145728LL, 3145728LL, 1048576LL);
}